// Round 1
// baseline (11627.823 us; speedup 1.0000x reference)
//
#include <hip/hip_runtime.h>
#include <math.h>

#define N_NODES 50000
#define N_EDGES 800000
#define G_GRAPHS 512
#define H_DIM 256
#define NF_DIM 32
#define EF_DIM 16
#define L_LAYERS 4
#define BN_EPS 1e-5f

// ---------------- h = x @ Win + bin ----------------
__global__ __launch_bounds__(256) void k_init_h(
    const float* __restrict__ x, const float* __restrict__ Win,
    const float* __restrict__ bin, float* __restrict__ h) {
  int row = blockIdx.x;
  int c = threadIdx.x;
  __shared__ float xs[NF_DIM];
  if (threadIdx.x < NF_DIM) xs[threadIdx.x] = x[(size_t)row * NF_DIM + threadIdx.x];
  __syncthreads();
  float acc = bin[c];
#pragma unroll
  for (int k = 0; k < NF_DIM; ++k) acc += xs[k] * Win[k * H_DIM + c];
  h[(size_t)row * H_DIM + c] = acc;
}

// ---------------- edge: msg = relu(h[src] + ea@We + be); aggr[dst] += msg ----
#define EDGES_PER_WAVE 4
__global__ __launch_bounds__(256) void k_edge(
    const float* __restrict__ eaG, const int* __restrict__ srcs,
    const int* __restrict__ dsts, const float* __restrict__ h,
    float* __restrict__ aggr, const float* __restrict__ We,
    const float* __restrict__ be) {
  __shared__ float WeS[EF_DIM * H_DIM];
  __shared__ float beS[H_DIM];
  for (int i = threadIdx.x; i < EF_DIM * H_DIM; i += 256) WeS[i] = We[i];
  if (threadIdx.x < H_DIM) beS[threadIdx.x] = be[threadIdx.x];
  __syncthreads();
  const int lane = threadIdx.x & 63;
  const int wave = threadIdx.x >> 6;
  const int c0 = lane * 4;
  const long e0 = (long)blockIdx.x * (4 * EDGES_PER_WAVE) + wave * EDGES_PER_WAVE;
  for (int q = 0; q < EDGES_PER_WAVE; ++q) {
    long e = e0 + q;
    if (e >= N_EDGES) break;
    int src = srcs[e];
    int dst = dsts[e];
    const float4* eap = (const float4*)(eaG + (size_t)e * EF_DIM);
    float4 ev0 = eap[0], ev1 = eap[1], ev2 = eap[2], ev3 = eap[3];
    float ev[16] = {ev0.x, ev0.y, ev0.z, ev0.w, ev1.x, ev1.y, ev1.z, ev1.w,
                    ev2.x, ev2.y, ev2.z, ev2.w, ev3.x, ev3.y, ev3.z, ev3.w};
    float4 acc = *(const float4*)&beS[c0];
#pragma unroll
    for (int k = 0; k < EF_DIM; ++k) {
      float4 wv = *(const float4*)&WeS[k * H_DIM + c0];
      acc.x += ev[k] * wv.x;
      acc.y += ev[k] * wv.y;
      acc.z += ev[k] * wv.z;
      acc.w += ev[k] * wv.w;
    }
    float4 hs = *(const float4*)&h[(size_t)src * H_DIM + c0];
    float m0 = fmaxf(hs.x + acc.x, 0.f);
    float m1 = fmaxf(hs.y + acc.y, 0.f);
    float m2 = fmaxf(hs.z + acc.z, 0.f);
    float m3 = fmaxf(hs.w + acc.w, 0.f);
    float* ap = aggr + (size_t)dst * H_DIM + c0;
    atomicAdd(ap + 0, m0);
    atomicAdd(ap + 1, m1);
    atomicAdd(ap + 2, m2);
    atomicAdd(ap + 3, m3);
  }
}

// ---------------- tiled fp32 GEMM, 64x64x16, 256 thr, 4x4 microtile --------
#define BM 64
#define BN 64
#define BK 16
#define ASTR 68  // padded LDS stride

// t1 = relu((h + aggr) @ W + bias)
__global__ __launch_bounds__(256) void k_gemm1(
    const float* __restrict__ h, const float* __restrict__ aggr,
    const float* __restrict__ W, const float* __restrict__ bias,
    float* __restrict__ out) {
  __shared__ float As[BK * ASTR];
  __shared__ float Bs[BK * ASTR];
  const int tid = threadIdx.x;
  const int bm = blockIdx.x * BM;
  const int bn = blockIdx.y * BN;
  const int tx = tid & 15, ty = tid >> 4;
  const int ar = tid >> 2;         // 0..63 (row in tile)
  const int ac = (tid & 3) * 4;    // 0,4,8,12 (k within tile)
  const int br = tid >> 4;         // 0..15 (k row)
  const int bc = (tid & 15) * 4;   // 0..60 (col)
  float acc[4][4] = {};
  for (int k0 = 0; k0 < H_DIM; k0 += BK) {
    int arow = bm + ar;
    float4 av = {0.f, 0.f, 0.f, 0.f};
    if (arow < N_NODES) {
      float4 hv = *(const float4*)&h[(size_t)arow * H_DIM + k0 + ac];
      float4 gv = *(const float4*)&aggr[(size_t)arow * H_DIM + k0 + ac];
      av.x = hv.x + gv.x; av.y = hv.y + gv.y; av.z = hv.z + gv.z; av.w = hv.w + gv.w;
    }
    As[(ac + 0) * ASTR + ar] = av.x;
    As[(ac + 1) * ASTR + ar] = av.y;
    As[(ac + 2) * ASTR + ar] = av.z;
    As[(ac + 3) * ASTR + ar] = av.w;
    *(float4*)&Bs[br * ASTR + bc] = *(const float4*)&W[(size_t)(k0 + br) * H_DIM + bn + bc];
    __syncthreads();
#pragma unroll
    for (int k = 0; k < BK; ++k) {
      float4 a4 = *(const float4*)&As[k * ASTR + ty * 4];
      float4 b4 = *(const float4*)&Bs[k * ASTR + tx * 4];
      float a[4] = {a4.x, a4.y, a4.z, a4.w};
      float b[4] = {b4.x, b4.y, b4.z, b4.w};
#pragma unroll
      for (int i = 0; i < 4; ++i)
#pragma unroll
        for (int j = 0; j < 4; ++j) acc[i][j] += a[i] * b[j];
    }
    __syncthreads();
  }
  const int col = bn + tx * 4;
  float4 bb = *(const float4*)&bias[col];
  float bbv[4] = {bb.x, bb.y, bb.z, bb.w};
#pragma unroll
  for (int i = 0; i < 4; ++i) {
    int row = bm + ty * 4 + i;
    if (row < N_NODES) {
      float4 o;
      o.x = fmaxf(acc[i][0] + bbv[0], 0.f);
      o.y = fmaxf(acc[i][1] + bbv[1], 0.f);
      o.z = fmaxf(acc[i][2] + bbv[2], 0.f);
      o.w = fmaxf(acc[i][3] + bbv[3], 0.f);
      *(float4*)&out[(size_t)row * H_DIM + col] = o;
    }
  }
}

// h += relu(bn(t1 @ W + bias))
__global__ __launch_bounds__(256) void k_gemm2(
    const float* __restrict__ t1, const float* __restrict__ W,
    const float* __restrict__ bias, const float* __restrict__ bnw,
    const float* __restrict__ bnb, const float* __restrict__ bnm,
    const float* __restrict__ bnv, float* __restrict__ h) {
  __shared__ float As[BK * ASTR];
  __shared__ float Bs[BK * ASTR];
  const int tid = threadIdx.x;
  const int bm = blockIdx.x * BM;
  const int bn = blockIdx.y * BN;
  const int tx = tid & 15, ty = tid >> 4;
  const int ar = tid >> 2;
  const int ac = (tid & 3) * 4;
  const int br = tid >> 4;
  const int bc = (tid & 15) * 4;
  float acc[4][4] = {};
  for (int k0 = 0; k0 < H_DIM; k0 += BK) {
    int arow = bm + ar;
    float4 av = {0.f, 0.f, 0.f, 0.f};
    if (arow < N_NODES) av = *(const float4*)&t1[(size_t)arow * H_DIM + k0 + ac];
    As[(ac + 0) * ASTR + ar] = av.x;
    As[(ac + 1) * ASTR + ar] = av.y;
    As[(ac + 2) * ASTR + ar] = av.z;
    As[(ac + 3) * ASTR + ar] = av.w;
    *(float4*)&Bs[br * ASTR + bc] = *(const float4*)&W[(size_t)(k0 + br) * H_DIM + bn + bc];
    __syncthreads();
#pragma unroll
    for (int k = 0; k < BK; ++k) {
      float4 a4 = *(const float4*)&As[k * ASTR + ty * 4];
      float4 b4 = *(const float4*)&Bs[k * ASTR + tx * 4];
      float a[4] = {a4.x, a4.y, a4.z, a4.w};
      float b[4] = {b4.x, b4.y, b4.z, b4.w};
#pragma unroll
      for (int i = 0; i < 4; ++i)
#pragma unroll
        for (int j = 0; j < 4; ++j) acc[i][j] += a[i] * b[j];
    }
    __syncthreads();
  }
  const int col = bn + tx * 4;
  float4 bb = *(const float4*)&bias[col];
  float4 w4 = *(const float4*)&bnw[col];
  float4 b4_ = *(const float4*)&bnb[col];
  float4 m4 = *(const float4*)&bnm[col];
  float4 v4 = *(const float4*)&bnv[col];
  float bbv[4] = {bb.x, bb.y, bb.z, bb.w};
  float sc[4] = {w4.x * rsqrtf(v4.x + BN_EPS), w4.y * rsqrtf(v4.y + BN_EPS),
                 w4.z * rsqrtf(v4.z + BN_EPS), w4.w * rsqrtf(v4.w + BN_EPS)};
  float mm[4] = {m4.x, m4.y, m4.z, m4.w};
  float sb[4] = {b4_.x, b4_.y, b4_.z, b4_.w};
#pragma unroll
  for (int i = 0; i < 4; ++i) {
    int row = bm + ty * 4 + i;
    if (row < N_NODES) {
      float4 hv = *(const float4*)&h[(size_t)row * H_DIM + col];
      float hvv[4] = {hv.x, hv.y, hv.z, hv.w};
      float o[4];
#pragma unroll
      for (int j = 0; j < 4; ++j) {
        float v = acc[i][j] + bbv[j];
        v = (v - mm[j]) * sc[j] + sb[j];
        o[j] = hvv[j] + fmaxf(v, 0.f);
      }
      float4 ov = {o[0], o[1], o[2], o[3]};
      *(float4*)&h[(size_t)row * H_DIM + col] = ov;
    }
  }
}

// ---------------- pooling: g[b] = sum over nodes (batch sorted) ------------
__global__ __launch_bounds__(256) void k_pool(
    const int* __restrict__ batch, const float* __restrict__ h,
    float* __restrict__ g, float* __restrict__ out_g) {
  int gid = blockIdx.x;
  int c = threadIdx.x;
  int lo = 0, hi = N_NODES;
  while (lo < hi) { int mid = (lo + hi) >> 1; if (batch[mid] < gid) lo = mid + 1; else hi = mid; }
  int start = lo;
  int lo2 = start, hi2 = N_NODES;
  while (lo2 < hi2) { int mid = (lo2 + hi2) >> 1; if (batch[mid] < gid + 1) lo2 = mid + 1; else hi2 = mid; }
  int end = lo2;
  float acc = 0.f;
  for (int n = start; n < end; ++n) acc += h[(size_t)n * H_DIM + c];
  g[(size_t)gid * H_DIM + c] = acc;
  out_g[(size_t)gid * H_DIM + c] = acc;
}

// ---------------- z1 = relu(g @ Wp1 + bp1)  (512x256 @ 256x128) ------------
__global__ __launch_bounds__(128) void k_p1(
    const float* __restrict__ g, const float* __restrict__ Wp1,
    const float* __restrict__ bp1, float* __restrict__ z1) {
  int gid = blockIdx.x;
  int c = threadIdx.x;
  __shared__ float gr[H_DIM];
  for (int i = threadIdx.x; i < H_DIM; i += 128) gr[i] = g[(size_t)gid * H_DIM + i];
  __syncthreads();
  float acc = bp1[c];
#pragma unroll 8
  for (int k = 0; k < H_DIM; ++k) acc += gr[k] * Wp1[k * 128 + c];
  z1[(size_t)gid * 128 + c] = fmaxf(acc, 0.f);
}

// ---------------- z = normalize(z1 @ Wp2 + bp2) ----------------------------
__global__ __launch_bounds__(64) void k_p2(
    const float* __restrict__ z1, const float* __restrict__ Wp2,
    const float* __restrict__ bp2, float* __restrict__ out) {
  int gid = blockIdx.x;
  int c = threadIdx.x;  // 64
  __shared__ float zr[128];
  for (int i = c; i < 128; i += 64) zr[i] = z1[(size_t)gid * 128 + i];
  __syncthreads();
  float acc = bp2[c];
#pragma unroll 8
  for (int k = 0; k < 128; ++k) acc += zr[k] * Wp2[k * 64 + c];
  float ss = acc * acc;
#pragma unroll
  for (int off = 32; off; off >>= 1) ss += __shfl_xor(ss, off);
  float nrm = fmaxf(sqrtf(ss), 1e-12f);
  out[2048 + (size_t)gid * 64 + c] = acc / nrm;
}

// ---------------- q1 = relu([g, gf] @ Wf1 + bf1) ---------------------------
__global__ __launch_bounds__(256) void k_f1(
    const float* __restrict__ g, const float* __restrict__ gf,
    const float* __restrict__ Wf1, const float* __restrict__ bf1,
    float* __restrict__ q1) {
  int gid = blockIdx.x;
  int c = threadIdx.x;  // 256
  __shared__ float r[H_DIM + NF_DIM];
  r[c] = g[(size_t)gid * H_DIM + c];
  if (c < NF_DIM) r[H_DIM + c] = gf[(size_t)gid * NF_DIM + c];
  __syncthreads();
  float acc = bf1[c];
#pragma unroll 8
  for (int k = 0; k < H_DIM + NF_DIM; ++k) acc += r[k] * Wf1[k * H_DIM + c];
  q1[(size_t)gid * H_DIM + c] = fmaxf(acc, 0.f);
}

// ---------------- q2 = relu(q1 @ Wf2 + bf2) --------------------------------
__global__ __launch_bounds__(128) void k_f2(
    const float* __restrict__ q1, const float* __restrict__ Wf2,
    const float* __restrict__ bf2, float* __restrict__ q2) {
  int gid = blockIdx.x;
  int c = threadIdx.x;  // 128
  __shared__ float r[H_DIM];
  for (int i = c; i < H_DIM; i += 128) r[i] = q1[(size_t)gid * H_DIM + i];
  __syncthreads();
  float acc = bf2[c];
#pragma unroll 8
  for (int k = 0; k < H_DIM; ++k) acc += r[k] * Wf2[k * 128 + c];
  q2[(size_t)gid * 128 + c] = fmaxf(acc, 0.f);
}

// ---------------- edl head -------------------------------------------------
__device__ __forceinline__ float softplusf(float x) {
  return fmaxf(x, 0.f) + log1pf(expf(-fabsf(x)));
}

__global__ __launch_bounds__(64) void k_head(
    const float* __restrict__ q2, const float* __restrict__ Wh,
    const float* __restrict__ bh, float* __restrict__ out) {
  int gid = blockIdx.x;
  int t = threadIdx.x;  // 64
  __shared__ float r[128];
  for (int i = t; i < 128; i += 64) r[i] = q2[(size_t)gid * 128 + i];
  __syncthreads();
  if (t < 4) {
    float acc = bh[t];
#pragma unroll 8
    for (int k = 0; k < 128; ++k) acc += r[k] * Wh[k * 4 + t];
    float v;
    if (t == 0) v = acc;
    else if (t == 2) v = softplusf(acc) + 1.f + 1e-6f;
    else v = softplusf(acc) + 1e-6f;
    out[(size_t)gid * 4 + t] = v;
  }
}

extern "C" void kernel_launch(void* const* d_in, const int* in_sizes, int n_in,
                              void* d_out, int out_size, void* d_ws, size_t ws_size,
                              hipStream_t stream) {
  const float* x     = (const float*)d_in[0];
  const int*   ei    = (const int*)d_in[1];
  const float* ea    = (const float*)d_in[2];
  const int*   batch = (const int*)d_in[3];
  const float* gf    = (const float*)d_in[4];
  const float* Win   = (const float*)d_in[5];
  const float* bin   = (const float*)d_in[6];
  const float* We    = (const float*)d_in[7];
  const float* be    = (const float*)d_in[8];
  const float* Wl1   = (const float*)d_in[9];
  const float* bl1   = (const float*)d_in[10];
  const float* Wl2   = (const float*)d_in[11];
  const float* bl2   = (const float*)d_in[12];
  const float* bnw   = (const float*)d_in[13];
  const float* bnb   = (const float*)d_in[14];
  const float* bnm   = (const float*)d_in[15];
  const float* bnv   = (const float*)d_in[16];
  const float* Wp1   = (const float*)d_in[17];
  const float* bp1   = (const float*)d_in[18];
  const float* Wp2   = (const float*)d_in[19];
  const float* bp2   = (const float*)d_in[20];
  const float* Wf1   = (const float*)d_in[21];
  const float* bf1   = (const float*)d_in[22];
  const float* Wf2   = (const float*)d_in[23];
  const float* bf2   = (const float*)d_in[24];
  const float* Wh    = (const float*)d_in[25];
  const float* bh    = (const float*)d_in[26];
  float* out = (float*)d_out;

  const size_t NH = (size_t)N_NODES * H_DIM;
  float* h    = (float*)d_ws;
  float* aggr = h + NH;
  float* t1   = aggr + NH;
  float* g    = t1 + NH;
  float* z1   = g + (size_t)G_GRAPHS * H_DIM;
  float* q1   = z1 + (size_t)G_GRAPHS * 128;
  float* q2   = q1 + (size_t)G_GRAPHS * H_DIM;

  k_init_h<<<N_NODES, 256, 0, stream>>>(x, Win, bin, h);

  for (int l = 0; l < L_LAYERS; ++l) {
    hipMemsetAsync(aggr, 0, NH * sizeof(float), stream);
    int eb = (N_EDGES + 4 * EDGES_PER_WAVE - 1) / (4 * EDGES_PER_WAVE);
    k_edge<<<eb, 256, 0, stream>>>(ea, ei, ei + N_EDGES, h, aggr,
                                   We + (size_t)l * EF_DIM * H_DIM, be + l * H_DIM);
    dim3 gg((N_NODES + BM - 1) / BM, H_DIM / BN);
    k_gemm1<<<gg, 256, 0, stream>>>(h, aggr, Wl1 + (size_t)l * H_DIM * H_DIM,
                                    bl1 + l * H_DIM, t1);
    k_gemm2<<<gg, 256, 0, stream>>>(t1, Wl2 + (size_t)l * H_DIM * H_DIM,
                                    bl2 + l * H_DIM, bnw + l * H_DIM, bnb + l * H_DIM,
                                    bnm + l * H_DIM, bnv + l * H_DIM, h);
  }

  float* out_g = out + 2048 + (size_t)G_GRAPHS * 64;  // edl(2048) + z(32768)
  k_pool<<<G_GRAPHS, 256, 0, stream>>>(batch, h, g, out_g);
  k_p1<<<G_GRAPHS, 128, 0, stream>>>(g, Wp1, bp1, z1);
  k_p2<<<G_GRAPHS, 64, 0, stream>>>(z1, Wp2, bp2, out);
  k_f1<<<G_GRAPHS, 256, 0, stream>>>(g, gf, Wf1, bf1, q1);
  k_f2<<<G_GRAPHS, 128, 0, stream>>>(q1, Wf2, bf2, q2);
  k_head<<<G_GRAPHS, 64, 0, stream>>>(q2, Wh, bh, out);
}

// Round 2
// 2186.169 us; speedup vs baseline: 5.3188x; 5.3188x over previous
//
#include <hip/hip_runtime.h>
#include <math.h>

#define N_NODES 50000
#define N_EDGES 800000
#define G_GRAPHS 512
#define H_DIM 256
#define NF_DIM 32
#define EF_DIM 16
#define L_LAYERS 4
#define BN_EPS 1e-5f

// ---------------- h = x @ Win + bin ----------------
__global__ __launch_bounds__(256) void k_init_h(
    const float* __restrict__ x, const float* __restrict__ Win,
    const float* __restrict__ bin, float* __restrict__ h) {
  int row = blockIdx.x;
  int c = threadIdx.x;
  __shared__ float xs[NF_DIM];
  if (threadIdx.x < NF_DIM) xs[threadIdx.x] = x[(size_t)row * NF_DIM + threadIdx.x];
  __syncthreads();
  float acc = bin[c];
#pragma unroll
  for (int k = 0; k < NF_DIM; ++k) acc += xs[k] * Win[k * H_DIM + c];
  h[(size_t)row * H_DIM + c] = acc;
}

// ---------------- CSR build ------------------------------------------------
__global__ __launch_bounds__(256) void k_deg(
    const int* __restrict__ dsts, int* __restrict__ deg) {
  int e = blockIdx.x * 256 + threadIdx.x;
  if (e < N_EDGES) atomicAdd(&deg[dsts[e]], 1);
}

#define SCAN_B 512
__global__ __launch_bounds__(SCAN_B) void k_scan1(
    const int* __restrict__ deg, int* __restrict__ incl, int* __restrict__ bsum) {
  __shared__ int s[SCAN_B];
  int gidx = blockIdx.x * SCAN_B + threadIdx.x;
  int v = (gidx < N_NODES) ? deg[gidx] : 0;
  s[threadIdx.x] = v;
  __syncthreads();
  for (int off = 1; off < SCAN_B; off <<= 1) {
    int t = (threadIdx.x >= off) ? s[threadIdx.x - off] : 0;
    __syncthreads();
    s[threadIdx.x] += t;
    __syncthreads();
  }
  if (gidx < N_NODES) incl[gidx] = s[threadIdx.x];
  if (threadIdx.x == SCAN_B - 1) bsum[blockIdx.x] = s[SCAN_B - 1];
}

__global__ void k_scan2(int* __restrict__ bsum, int nb) {
  if (threadIdx.x == 0 && blockIdx.x == 0) {
    int acc = 0;
    for (int i = 0; i < nb; ++i) { int t = bsum[i]; bsum[i] = acc; acc += t; }
  }
}

__global__ __launch_bounds__(SCAN_B) void k_scan3(
    const int* __restrict__ incl, const int* __restrict__ deg,
    const int* __restrict__ bsum, int* __restrict__ off) {
  int gidx = blockIdx.x * SCAN_B + threadIdx.x;
  if (gidx < N_NODES) off[gidx] = incl[gidx] - deg[gidx] + bsum[blockIdx.x];
  if (gidx == 0) off[N_NODES] = N_EDGES;
}

__global__ __launch_bounds__(256) void k_scatter(
    const int* __restrict__ dsts, const int* __restrict__ off,
    int* __restrict__ fill, int* __restrict__ eid) {
  int e = blockIdx.x * 256 + threadIdx.x;
  if (e < N_EDGES) {
    int d = dsts[e];
    int pos = atomicAdd(&fill[d], 1);
    eid[off[d] + pos] = e;
  }
}

// ---------------- aggregation: t0 = h + sum_dst relu(h[src] + ea@We + be) --
__global__ __launch_bounds__(256) void k_aggr(
    const int* __restrict__ off, const int* __restrict__ eid,
    const int* __restrict__ srcs, const float* __restrict__ ea,
    const float* __restrict__ h, const float* __restrict__ We,
    const float* __restrict__ be, float* __restrict__ t0) {
  int n = blockIdx.x;
  int c = threadIdx.x;
  float w[EF_DIM];
#pragma unroll
  for (int k = 0; k < EF_DIM; ++k) w[k] = We[k * H_DIM + c];
  const float bec = be[c];
  const int s0 = off[n], s1 = off[n + 1];
  float acc = 0.f;
  for (int i = s0; i < s1; ++i) {
    int e = eid[i];
    int src = srcs[e];
    const float4* eap = (const float4*)(ea + (size_t)e * EF_DIM);
    float4 e0 = eap[0], e1 = eap[1], e2 = eap[2], e3 = eap[3];
    float ev[EF_DIM] = {e0.x, e0.y, e0.z, e0.w, e1.x, e1.y, e1.z, e1.w,
                        e2.x, e2.y, e2.z, e2.w, e3.x, e3.y, e3.z, e3.w};
    float m = bec;
#pragma unroll
    for (int k = 0; k < EF_DIM; ++k) m += ev[k] * w[k];
    m += h[(size_t)src * H_DIM + c];
    acc += fmaxf(m, 0.f);
  }
  t0[(size_t)n * H_DIM + c] = h[(size_t)n * H_DIM + c] + acc;
}

// ---------------- tiled fp32 GEMM, 64x64x16, 256 thr, 4x4 microtile --------
#define BM 64
#define BN 64
#define BK 16
#define ASTR 68  // padded LDS stride

// t1 = relu(t0 @ W + bias)
__global__ __launch_bounds__(256) void k_gemm1(
    const float* __restrict__ t0, const float* __restrict__ W,
    const float* __restrict__ bias, float* __restrict__ out) {
  __shared__ float As[BK * ASTR];
  __shared__ float Bs[BK * ASTR];
  const int tid = threadIdx.x;
  const int bm = blockIdx.x * BM;
  const int bn = blockIdx.y * BN;
  const int tx = tid & 15, ty = tid >> 4;
  const int ar = tid >> 2;         // 0..63 (row in tile)
  const int ac = (tid & 3) * 4;    // 0,4,8,12 (k within tile)
  const int br = tid >> 4;         // 0..15 (k row)
  const int bc = (tid & 15) * 4;   // 0..60 (col)
  float acc[4][4] = {};
  for (int k0 = 0; k0 < H_DIM; k0 += BK) {
    int arow = bm + ar;
    float4 av = {0.f, 0.f, 0.f, 0.f};
    if (arow < N_NODES) av = *(const float4*)&t0[(size_t)arow * H_DIM + k0 + ac];
    As[(ac + 0) * ASTR + ar] = av.x;
    As[(ac + 1) * ASTR + ar] = av.y;
    As[(ac + 2) * ASTR + ar] = av.z;
    As[(ac + 3) * ASTR + ar] = av.w;
    *(float4*)&Bs[br * ASTR + bc] = *(const float4*)&W[(size_t)(k0 + br) * H_DIM + bn + bc];
    __syncthreads();
#pragma unroll
    for (int k = 0; k < BK; ++k) {
      float4 a4 = *(const float4*)&As[k * ASTR + ty * 4];
      float4 b4 = *(const float4*)&Bs[k * ASTR + tx * 4];
      float a[4] = {a4.x, a4.y, a4.z, a4.w};
      float b[4] = {b4.x, b4.y, b4.z, b4.w};
#pragma unroll
      for (int i = 0; i < 4; ++i)
#pragma unroll
        for (int j = 0; j < 4; ++j) acc[i][j] += a[i] * b[j];
    }
    __syncthreads();
  }
  const int col = bn + tx * 4;
  float4 bb = *(const float4*)&bias[col];
  float bbv[4] = {bb.x, bb.y, bb.z, bb.w};
#pragma unroll
  for (int i = 0; i < 4; ++i) {
    int row = bm + ty * 4 + i;
    if (row < N_NODES) {
      float4 o;
      o.x = fmaxf(acc[i][0] + bbv[0], 0.f);
      o.y = fmaxf(acc[i][1] + bbv[1], 0.f);
      o.z = fmaxf(acc[i][2] + bbv[2], 0.f);
      o.w = fmaxf(acc[i][3] + bbv[3], 0.f);
      *(float4*)&out[(size_t)row * H_DIM + col] = o;
    }
  }
}

// h += relu(bn(t1 @ W + bias))
__global__ __launch_bounds__(256) void k_gemm2(
    const float* __restrict__ t1, const float* __restrict__ W,
    const float* __restrict__ bias, const float* __restrict__ bnw,
    const float* __restrict__ bnb, const float* __restrict__ bnm,
    const float* __restrict__ bnv, float* __restrict__ h) {
  __shared__ float As[BK * ASTR];
  __shared__ float Bs[BK * ASTR];
  const int tid = threadIdx.x;
  const int bm = blockIdx.x * BM;
  const int bn = blockIdx.y * BN;
  const int tx = tid & 15, ty = tid >> 4;
  const int ar = tid >> 2;
  const int ac = (tid & 3) * 4;
  const int br = tid >> 4;
  const int bc = (tid & 15) * 4;
  float acc[4][4] = {};
  for (int k0 = 0; k0 < H_DIM; k0 += BK) {
    int arow = bm + ar;
    float4 av = {0.f, 0.f, 0.f, 0.f};
    if (arow < N_NODES) av = *(const float4*)&t1[(size_t)arow * H_DIM + k0 + ac];
    As[(ac + 0) * ASTR + ar] = av.x;
    As[(ac + 1) * ASTR + ar] = av.y;
    As[(ac + 2) * ASTR + ar] = av.z;
    As[(ac + 3) * ASTR + ar] = av.w;
    *(float4*)&Bs[br * ASTR + bc] = *(const float4*)&W[(size_t)(k0 + br) * H_DIM + bn + bc];
    __syncthreads();
#pragma unroll
    for (int k = 0; k < BK; ++k) {
      float4 a4 = *(const float4*)&As[k * ASTR + ty * 4];
      float4 b4 = *(const float4*)&Bs[k * ASTR + tx * 4];
      float a[4] = {a4.x, a4.y, a4.z, a4.w};
      float b[4] = {b4.x, b4.y, b4.z, b4.w};
#pragma unroll
      for (int i = 0; i < 4; ++i)
#pragma unroll
        for (int j = 0; j < 4; ++j) acc[i][j] += a[i] * b[j];
    }
    __syncthreads();
  }
  const int col = bn + tx * 4;
  float4 bb = *(const float4*)&bias[col];
  float4 w4 = *(const float4*)&bnw[col];
  float4 b4_ = *(const float4*)&bnb[col];
  float4 m4 = *(const float4*)&bnm[col];
  float4 v4 = *(const float4*)&bnv[col];
  float bbv[4] = {bb.x, bb.y, bb.z, bb.w};
  float sc[4] = {w4.x * rsqrtf(v4.x + BN_EPS), w4.y * rsqrtf(v4.y + BN_EPS),
                 w4.z * rsqrtf(v4.z + BN_EPS), w4.w * rsqrtf(v4.w + BN_EPS)};
  float mm[4] = {m4.x, m4.y, m4.z, m4.w};
  float sb[4] = {b4_.x, b4_.y, b4_.z, b4_.w};
#pragma unroll
  for (int i = 0; i < 4; ++i) {
    int row = bm + ty * 4 + i;
    if (row < N_NODES) {
      float4 hv = *(const float4*)&h[(size_t)row * H_DIM + col];
      float hvv[4] = {hv.x, hv.y, hv.z, hv.w};
      float o[4];
#pragma unroll
      for (int j = 0; j < 4; ++j) {
        float v = acc[i][j] + bbv[j];
        v = (v - mm[j]) * sc[j] + sb[j];
        o[j] = hvv[j] + fmaxf(v, 0.f);
      }
      float4 ov = {o[0], o[1], o[2], o[3]};
      *(float4*)&h[(size_t)row * H_DIM + col] = ov;
    }
  }
}

// ---------------- pooling: g[b] = sum over nodes (batch sorted) ------------
__global__ __launch_bounds__(256) void k_pool(
    const int* __restrict__ batch, const float* __restrict__ h,
    float* __restrict__ g, float* __restrict__ out_g) {
  int gid = blockIdx.x;
  int c = threadIdx.x;
  int lo = 0, hi = N_NODES;
  while (lo < hi) { int mid = (lo + hi) >> 1; if (batch[mid] < gid) lo = mid + 1; else hi = mid; }
  int start = lo;
  int lo2 = start, hi2 = N_NODES;
  while (lo2 < hi2) { int mid = (lo2 + hi2) >> 1; if (batch[mid] < gid + 1) lo2 = mid + 1; else hi2 = mid; }
  int end = lo2;
  float acc = 0.f;
  for (int n = start; n < end; ++n) acc += h[(size_t)n * H_DIM + c];
  g[(size_t)gid * H_DIM + c] = acc;
  out_g[(size_t)gid * H_DIM + c] = acc;
}

// ---------------- z1 = relu(g @ Wp1 + bp1)  (512x256 @ 256x128) ------------
__global__ __launch_bounds__(128) void k_p1(
    const float* __restrict__ g, const float* __restrict__ Wp1,
    const float* __restrict__ bp1, float* __restrict__ z1) {
  int gid = blockIdx.x;
  int c = threadIdx.x;
  __shared__ float gr[H_DIM];
  for (int i = threadIdx.x; i < H_DIM; i += 128) gr[i] = g[(size_t)gid * H_DIM + i];
  __syncthreads();
  float acc = bp1[c];
#pragma unroll 8
  for (int k = 0; k < H_DIM; ++k) acc += gr[k] * Wp1[k * 128 + c];
  z1[(size_t)gid * 128 + c] = fmaxf(acc, 0.f);
}

// ---------------- z = normalize(z1 @ Wp2 + bp2) ----------------------------
__global__ __launch_bounds__(64) void k_p2(
    const float* __restrict__ z1, const float* __restrict__ Wp2,
    const float* __restrict__ bp2, float* __restrict__ out) {
  int gid = blockIdx.x;
  int c = threadIdx.x;  // 64
  __shared__ float zr[128];
  for (int i = c; i < 128; i += 64) zr[i] = z1[(size_t)gid * 128 + i];
  __syncthreads();
  float acc = bp2[c];
#pragma unroll 8
  for (int k = 0; k < 128; ++k) acc += zr[k] * Wp2[k * 64 + c];
  float ss = acc * acc;
#pragma unroll
  for (int off = 32; off; off >>= 1) ss += __shfl_xor(ss, off);
  float nrm = fmaxf(sqrtf(ss), 1e-12f);
  out[2048 + (size_t)gid * 64 + c] = acc / nrm;
}

// ---------------- q1 = relu([g, gf] @ Wf1 + bf1) ---------------------------
__global__ __launch_bounds__(256) void k_f1(
    const float* __restrict__ g, const float* __restrict__ gf,
    const float* __restrict__ Wf1, const float* __restrict__ bf1,
    float* __restrict__ q1) {
  int gid = blockIdx.x;
  int c = threadIdx.x;  // 256
  __shared__ float r[H_DIM + NF_DIM];
  r[c] = g[(size_t)gid * H_DIM + c];
  if (c < NF_DIM) r[H_DIM + c] = gf[(size_t)gid * NF_DIM + c];
  __syncthreads();
  float acc = bf1[c];
#pragma unroll 8
  for (int k = 0; k < H_DIM + NF_DIM; ++k) acc += r[k] * Wf1[k * H_DIM + c];
  q1[(size_t)gid * H_DIM + c] = fmaxf(acc, 0.f);
}

// ---------------- q2 = relu(q1 @ Wf2 + bf2) --------------------------------
__global__ __launch_bounds__(128) void k_f2(
    const float* __restrict__ q1, const float* __restrict__ Wf2,
    const float* __restrict__ bf2, float* __restrict__ q2) {
  int gid = blockIdx.x;
  int c = threadIdx.x;  // 128
  __shared__ float r[H_DIM];
  for (int i = c; i < H_DIM; i += 128) r[i] = q1[(size_t)gid * H_DIM + i];
  __syncthreads();
  float acc = bf2[c];
#pragma unroll 8
  for (int k = 0; k < H_DIM; ++k) acc += r[k] * Wf2[k * 128 + c];
  q2[(size_t)gid * 128 + c] = fmaxf(acc, 0.f);
}

// ---------------- edl head -------------------------------------------------
__device__ __forceinline__ float softplusf(float x) {
  return fmaxf(x, 0.f) + log1pf(expf(-fabsf(x)));
}

__global__ __launch_bounds__(64) void k_head(
    const float* __restrict__ q2, const float* __restrict__ Wh,
    const float* __restrict__ bh, float* __restrict__ out) {
  int gid = blockIdx.x;
  int t = threadIdx.x;  // 64
  __shared__ float r[128];
  for (int i = t; i < 128; i += 64) r[i] = q2[(size_t)gid * 128 + i];
  __syncthreads();
  if (t < 4) {
    float acc = bh[t];
#pragma unroll 8
    for (int k = 0; k < 128; ++k) acc += r[k] * Wh[k * 4 + t];
    float v;
    if (t == 0) v = acc;
    else if (t == 2) v = softplusf(acc) + 1.f + 1e-6f;
    else v = softplusf(acc) + 1e-6f;
    out[(size_t)gid * 4 + t] = v;
  }
}

extern "C" void kernel_launch(void* const* d_in, const int* in_sizes, int n_in,
                              void* d_out, int out_size, void* d_ws, size_t ws_size,
                              hipStream_t stream) {
  const float* x     = (const float*)d_in[0];
  const int*   ei    = (const int*)d_in[1];
  const float* ea    = (const float*)d_in[2];
  const int*   batch = (const int*)d_in[3];
  const float* gf    = (const float*)d_in[4];
  const float* Win   = (const float*)d_in[5];
  const float* bin   = (const float*)d_in[6];
  const float* We    = (const float*)d_in[7];
  const float* be    = (const float*)d_in[8];
  const float* Wl1   = (const float*)d_in[9];
  const float* bl1   = (const float*)d_in[10];
  const float* Wl2   = (const float*)d_in[11];
  const float* bl2   = (const float*)d_in[12];
  const float* bnw   = (const float*)d_in[13];
  const float* bnb   = (const float*)d_in[14];
  const float* bnm   = (const float*)d_in[15];
  const float* bnv   = (const float*)d_in[16];
  const float* Wp1   = (const float*)d_in[17];
  const float* bp1   = (const float*)d_in[18];
  const float* Wp2   = (const float*)d_in[19];
  const float* bp2   = (const float*)d_in[20];
  const float* Wf1   = (const float*)d_in[21];
  const float* bf1   = (const float*)d_in[22];
  const float* Wf2   = (const float*)d_in[23];
  const float* bf2   = (const float*)d_in[24];
  const float* Wh    = (const float*)d_in[25];
  const float* bh    = (const float*)d_in[26];
  float* out = (float*)d_out;

  const int* srcs = ei;
  const int* dsts = ei + N_EDGES;

  const size_t NH = (size_t)N_NODES * H_DIM;
  float* h    = (float*)d_ws;
  float* t0   = h + NH;
  float* t1   = t0 + NH;
  float* g    = t1 + NH;
  float* z1   = g + (size_t)G_GRAPHS * H_DIM;
  float* q1   = z1 + (size_t)G_GRAPHS * 128;
  float* q2   = q1 + (size_t)G_GRAPHS * H_DIM;
  int* deg  = (int*)(q2 + (size_t)G_GRAPHS * 128);
  int* fill = deg + N_NODES;
  int* incl = fill + N_NODES;
  int* off  = incl + N_NODES;          // N_NODES + 1
  int* bsum = off + N_NODES + 1;       // up to 128
  int* eid  = bsum + 128;              // N_EDGES

  // ---- CSR build (edge_index is layer-invariant: build once per launch) ----
  hipMemsetAsync(deg, 0, N_NODES * sizeof(int), stream);
  hipMemsetAsync(fill, 0, N_NODES * sizeof(int), stream);
  const int nscan = (N_NODES + SCAN_B - 1) / SCAN_B;
  k_deg<<<(N_EDGES + 255) / 256, 256, 0, stream>>>(dsts, deg);
  k_scan1<<<nscan, SCAN_B, 0, stream>>>(deg, incl, bsum);
  k_scan2<<<1, 64, 0, stream>>>(bsum, nscan);
  k_scan3<<<nscan, SCAN_B, 0, stream>>>(incl, deg, bsum, off);
  k_scatter<<<(N_EDGES + 255) / 256, 256, 0, stream>>>(dsts, off, fill, eid);

  k_init_h<<<N_NODES, 256, 0, stream>>>(x, Win, bin, h);

  for (int l = 0; l < L_LAYERS; ++l) {
    k_aggr<<<N_NODES, 256, 0, stream>>>(off, eid, srcs, ea, h,
                                        We + (size_t)l * EF_DIM * H_DIM,
                                        be + l * H_DIM, t0);
    dim3 gg((N_NODES + BM - 1) / BM, H_DIM / BN);
    k_gemm1<<<gg, 256, 0, stream>>>(t0, Wl1 + (size_t)l * H_DIM * H_DIM,
                                    bl1 + l * H_DIM, t1);
    k_gemm2<<<gg, 256, 0, stream>>>(t1, Wl2 + (size_t)l * H_DIM * H_DIM,
                                    bl2 + l * H_DIM, bnw + l * H_DIM, bnb + l * H_DIM,
                                    bnm + l * H_DIM, bnv + l * H_DIM, h);
  }

  float* out_g = out + 2048 + (size_t)G_GRAPHS * 64;  // edl(2048) + z(32768)
  k_pool<<<G_GRAPHS, 256, 0, stream>>>(batch, h, g, out_g);
  k_p1<<<G_GRAPHS, 128, 0, stream>>>(g, Wp1, bp1, z1);
  k_p2<<<G_GRAPHS, 64, 0, stream>>>(z1, Wp2, bp2, out);
  k_f1<<<G_GRAPHS, 256, 0, stream>>>(g, gf, Wf1, bf1, q1);
  k_f2<<<G_GRAPHS, 128, 0, stream>>>(q1, Wf2, bf2, q2);
  k_head<<<G_GRAPHS, 64, 0, stream>>>(q2, Wh, bh, out);
}

// Round 3
// 1368.424 us; speedup vs baseline: 8.4972x; 1.5976x over previous
//
#include <hip/hip_runtime.h>
#include <math.h>

#define N_NODES 50000
#define N_EDGES 800000
#define G_GRAPHS 512
#define H_DIM 256
#define NF_DIM 32
#define EF_DIM 16
#define L_LAYERS 4
#define BN_EPS 1e-5f

typedef __bf16 bf16_t;
typedef __attribute__((ext_vector_type(8))) __bf16 bf16x8;
typedef __attribute__((ext_vector_type(4))) float f32x4;

// ---------------- h = x @ Win + bin ----------------
__global__ __launch_bounds__(256) void k_init_h(
    const float* __restrict__ x, const float* __restrict__ Win,
    const float* __restrict__ bin, float* __restrict__ h) {
  int row = blockIdx.x;
  int c = threadIdx.x;
  __shared__ float xs[NF_DIM];
  if (threadIdx.x < NF_DIM) xs[threadIdx.x] = x[(size_t)row * NF_DIM + threadIdx.x];
  __syncthreads();
  float acc = bin[c];
#pragma unroll
  for (int k = 0; k < NF_DIM; ++k) acc += xs[k] * Win[k * H_DIM + c];
  h[(size_t)row * H_DIM + c] = acc;
}

// ---------------- weight transpose + bf16 cast: Wt[l][n][k] = W[l][k][n] ---
__global__ __launch_bounds__(256) void k_prepW(
    const float* __restrict__ W, bf16_t* __restrict__ Wt) {
  int n = blockIdx.x;          // 0..255
  int l = blockIdx.y;          // 0..3
  int k = threadIdx.x;         // 0..255
  Wt[(size_t)l * 65536 + n * 256 + k] = (bf16_t)W[(size_t)l * 65536 + k * 256 + n];
}

// ---------------- CSR build ------------------------------------------------
__global__ __launch_bounds__(256) void k_deg(
    const int* __restrict__ dsts, int* __restrict__ deg) {
  int e = blockIdx.x * 256 + threadIdx.x;
  if (e < N_EDGES) atomicAdd(&deg[dsts[e]], 1);
}

#define SCAN_B 512
__global__ __launch_bounds__(SCAN_B) void k_scan1(
    const int* __restrict__ deg, int* __restrict__ incl, int* __restrict__ bsum) {
  __shared__ int s[SCAN_B];
  int gidx = blockIdx.x * SCAN_B + threadIdx.x;
  int v = (gidx < N_NODES) ? deg[gidx] : 0;
  s[threadIdx.x] = v;
  __syncthreads();
  for (int off = 1; off < SCAN_B; off <<= 1) {
    int t = (threadIdx.x >= off) ? s[threadIdx.x - off] : 0;
    __syncthreads();
    s[threadIdx.x] += t;
    __syncthreads();
  }
  if (gidx < N_NODES) incl[gidx] = s[threadIdx.x];
  if (threadIdx.x == SCAN_B - 1) bsum[blockIdx.x] = s[SCAN_B - 1];
}

__global__ void k_scan2(int* __restrict__ bsum, int nb) {
  if (threadIdx.x == 0 && blockIdx.x == 0) {
    int acc = 0;
    for (int i = 0; i < nb; ++i) { int t = bsum[i]; bsum[i] = acc; acc += t; }
  }
}

__global__ __launch_bounds__(SCAN_B) void k_scan3(
    const int* __restrict__ incl, const int* __restrict__ deg,
    const int* __restrict__ bsum, int* __restrict__ off) {
  int gidx = blockIdx.x * SCAN_B + threadIdx.x;
  if (gidx < N_NODES) off[gidx] = incl[gidx] - deg[gidx] + bsum[blockIdx.x];
  if (gidx == 0) off[N_NODES] = N_EDGES;
}

__global__ __launch_bounds__(256) void k_scatter(
    const int* __restrict__ srcs, const int* __restrict__ dsts,
    const int* __restrict__ off, int* __restrict__ fill,
    int* __restrict__ eid, int* __restrict__ src_csr) {
  int e = blockIdx.x * 256 + threadIdx.x;
  if (e < N_EDGES) {
    int d = dsts[e];
    int pos = atomicAdd(&fill[d], 1);
    int idx = off[d] + pos;
    eid[idx] = e;
    src_csr[idx] = srcs[e];
  }
}

// ---------------- aggregation: t0b = bf16(h + sum relu(h[src] + ea@We + be))
__device__ __forceinline__ float edge_dot(const float* __restrict__ ea, int e,
                                          const float* __restrict__ w, float m) {
  const f32x4* p = (const f32x4*)(ea + (size_t)e * EF_DIM);
  f32x4 v0 = p[0], v1 = p[1], v2 = p[2], v3 = p[3];
  m += v0.x * w[0] + v0.y * w[1] + v0.z * w[2] + v0.w * w[3];
  m += v1.x * w[4] + v1.y * w[5] + v1.z * w[6] + v1.w * w[7];
  m += v2.x * w[8] + v2.y * w[9] + v2.z * w[10] + v2.w * w[11];
  m += v3.x * w[12] + v3.y * w[13] + v3.z * w[14] + v3.w * w[15];
  return m;
}

__global__ __launch_bounds__(256) void k_aggr(
    const int* __restrict__ off, const int* __restrict__ src_csr,
    const int* __restrict__ eid, const float* __restrict__ ea,
    const float* __restrict__ h, const float* __restrict__ We,
    const float* __restrict__ be, bf16_t* __restrict__ t0b) {
  int n = blockIdx.x;
  int c = threadIdx.x;
  float w[EF_DIM];
#pragma unroll
  for (int k = 0; k < EF_DIM; ++k) w[k] = We[k * H_DIM + c];
  const float bec = be[c];
  const int s0 = off[n], s1 = off[n + 1];
  float acc = 0.f;
  int i = s0;
  for (; i + 4 <= s1; i += 4) {
    // batch all independent loads: 4 src, 4 eid, then 4 h-gathers + 4 ea rows
    int sA = src_csr[i], sB = src_csr[i + 1], sC = src_csr[i + 2], sD = src_csr[i + 3];
    int eA = eid[i], eB = eid[i + 1], eC = eid[i + 2], eD = eid[i + 3];
    float hA = h[(size_t)sA * H_DIM + c];
    float hB = h[(size_t)sB * H_DIM + c];
    float hC = h[(size_t)sC * H_DIM + c];
    float hD = h[(size_t)sD * H_DIM + c];
    float mA = edge_dot(ea, eA, w, bec);
    float mB = edge_dot(ea, eB, w, bec);
    float mC = edge_dot(ea, eC, w, bec);
    float mD = edge_dot(ea, eD, w, bec);
    acc += fmaxf(mA + hA, 0.f) + fmaxf(mB + hB, 0.f) +
           fmaxf(mC + hC, 0.f) + fmaxf(mD + hD, 0.f);
  }
  for (; i < s1; ++i) {
    int s = src_csr[i];
    int e = eid[i];
    float hv = h[(size_t)s * H_DIM + c];
    float m = edge_dot(ea, e, w, bec);
    acc += fmaxf(m + hv, 0.f);
  }
  float hn = h[(size_t)n * H_DIM + c];
  t0b[(size_t)n * H_DIM + c] = (bf16_t)(hn + acc);
}

// ---------------- bf16 MFMA GEMM: 128x128 tile, 4 waves, 4x4 frags ---------
// EPI 0: outb = bf16(relu(A@B + bias))      (t1 = relu(t0 @ Wl1 + bl1))
// EPI 1: outf += relu(bn(A@B + bias))       (h += relu(bn(t1 @ Wl2 + bl2)))
#define GBM 128
#define GBN 128
#define GBK 32
#define LSTR 40  // bf16 elems per LDS row (32 + 8 pad; 80B, 16B-aligned)

template <int EPI>
__global__ __launch_bounds__(256) void k_mm(
    const bf16_t* __restrict__ A, const bf16_t* __restrict__ Bt,
    const float* __restrict__ bias, const float* __restrict__ bnw,
    const float* __restrict__ bnb, const float* __restrict__ bnm,
    const float* __restrict__ bnv, bf16_t* __restrict__ outb,
    float* __restrict__ outf) {
  __shared__ bf16_t As[GBM * LSTR];
  __shared__ bf16_t Bs[GBN * LSTR];
  const int tid = threadIdx.x;
  const int bm = blockIdx.x * GBM;
  const int bn = blockIdx.y * GBN;
  const int lane = tid & 63;
  const int wv = tid >> 6;
  const int wm = (wv & 1) * 64;
  const int wn = (wv >> 1) * 64;
  const int l15 = lane & 15;
  const int kg = lane >> 4;  // 0..3
  f32x4 acc[4][4] = {};
  for (int k0 = 0; k0 < H_DIM; k0 += GBK) {
    for (int i = tid; i < GBM * 4; i += 256) {
      int row = i >> 2, ch = (i & 3) * 8;
      int grow = bm + row;
      f32x4 v = {0.f, 0.f, 0.f, 0.f};
      if (grow < N_NODES) v = *(const f32x4*)&A[(size_t)grow * H_DIM + k0 + ch];
      *(f32x4*)&As[row * LSTR + ch] = v;
    }
    for (int i = tid; i < GBN * 4; i += 256) {
      int row = i >> 2, ch = (i & 3) * 8;
      *(f32x4*)&Bs[row * LSTR + ch] =
          *(const f32x4*)&Bt[(size_t)(bn + row) * H_DIM + k0 + ch];
    }
    __syncthreads();
    bf16x8 af[4], bf[4];
#pragma unroll
    for (int m = 0; m < 4; ++m)
      af[m] = *(const bf16x8*)&As[(wm + m * 16 + l15) * LSTR + kg * 8];
#pragma unroll
    for (int n = 0; n < 4; ++n)
      bf[n] = *(const bf16x8*)&Bs[(wn + n * 16 + l15) * LSTR + kg * 8];
#pragma unroll
    for (int m = 0; m < 4; ++m)
#pragma unroll
      for (int n = 0; n < 4; ++n)
        acc[m][n] =
            __builtin_amdgcn_mfma_f32_16x16x32_bf16(af[m], bf[n], acc[m][n], 0, 0, 0);
    __syncthreads();
  }
  // epilogue: D[row=(kg*4+r)][col=l15] per fragment
#pragma unroll
  for (int m = 0; m < 4; ++m) {
    int row = bm + wm + m * 16 + kg * 4;
#pragma unroll
    for (int n = 0; n < 4; ++n) {
      int col = bn + wn + n * 16 + l15;
      float bi = bias[col];
      if constexpr (EPI == 0) {
#pragma unroll
        for (int r = 0; r < 4; ++r) {
          int rr = row + r;
          if (rr < N_NODES)
            outb[(size_t)rr * H_DIM + col] = (bf16_t)fmaxf(acc[m][n][r] + bi, 0.f);
        }
      } else {
        float sc = bnw[col] * rsqrtf(bnv[col] + BN_EPS);
        float mu = bnm[col];
        float sb = bnb[col];
#pragma unroll
        for (int r = 0; r < 4; ++r) {
          int rr = row + r;
          if (rr < N_NODES) {
            float v = (acc[m][n][r] + bi - mu) * sc + sb;
            float* hp = &outf[(size_t)rr * H_DIM + col];
            *hp = *hp + fmaxf(v, 0.f);
          }
        }
      }
    }
  }
}

// ---------------- pooling: g[b] = sum over nodes (batch sorted) ------------
__global__ __launch_bounds__(256) void k_pool(
    const int* __restrict__ batch, const float* __restrict__ h,
    float* __restrict__ g, float* __restrict__ out_g) {
  int gid = blockIdx.x;
  int c = threadIdx.x;
  int lo = 0, hi = N_NODES;
  while (lo < hi) { int mid = (lo + hi) >> 1; if (batch[mid] < gid) lo = mid + 1; else hi = mid; }
  int start = lo;
  int lo2 = start, hi2 = N_NODES;
  while (lo2 < hi2) { int mid = (lo2 + hi2) >> 1; if (batch[mid] < gid + 1) lo2 = mid + 1; else hi2 = mid; }
  int end = lo2;
  float acc = 0.f;
  for (int n = start; n < end; ++n) acc += h[(size_t)n * H_DIM + c];
  g[(size_t)gid * H_DIM + c] = acc;
  out_g[(size_t)gid * H_DIM + c] = acc;
}

// ---------------- z1 = relu(g @ Wp1 + bp1) ---------------------------------
__global__ __launch_bounds__(128) void k_p1(
    const float* __restrict__ g, const float* __restrict__ Wp1,
    const float* __restrict__ bp1, float* __restrict__ z1) {
  int gid = blockIdx.x;
  int c = threadIdx.x;
  __shared__ float gr[H_DIM];
  for (int i = threadIdx.x; i < H_DIM; i += 128) gr[i] = g[(size_t)gid * H_DIM + i];
  __syncthreads();
  float acc = bp1[c];
#pragma unroll 8
  for (int k = 0; k < H_DIM; ++k) acc += gr[k] * Wp1[k * 128 + c];
  z1[(size_t)gid * 128 + c] = fmaxf(acc, 0.f);
}

// ---------------- z = normalize(z1 @ Wp2 + bp2) ----------------------------
__global__ __launch_bounds__(64) void k_p2(
    const float* __restrict__ z1, const float* __restrict__ Wp2,
    const float* __restrict__ bp2, float* __restrict__ out) {
  int gid = blockIdx.x;
  int c = threadIdx.x;
  __shared__ float zr[128];
  for (int i = c; i < 128; i += 64) zr[i] = z1[(size_t)gid * 128 + i];
  __syncthreads();
  float acc = bp2[c];
#pragma unroll 8
  for (int k = 0; k < 128; ++k) acc += zr[k] * Wp2[k * 64 + c];
  float ss = acc * acc;
#pragma unroll
  for (int off = 32; off; off >>= 1) ss += __shfl_xor(ss, off);
  float nrm = fmaxf(sqrtf(ss), 1e-12f);
  out[2048 + (size_t)gid * 64 + c] = acc / nrm;
}

// ---------------- q1 = relu([g, gf] @ Wf1 + bf1) ---------------------------
__global__ __launch_bounds__(256) void k_f1(
    const float* __restrict__ g, const float* __restrict__ gf,
    const float* __restrict__ Wf1, const float* __restrict__ bf1,
    float* __restrict__ q1) {
  int gid = blockIdx.x;
  int c = threadIdx.x;
  __shared__ float r[H_DIM + NF_DIM];
  r[c] = g[(size_t)gid * H_DIM + c];
  if (c < NF_DIM) r[H_DIM + c] = gf[(size_t)gid * NF_DIM + c];
  __syncthreads();
  float acc = bf1[c];
#pragma unroll 8
  for (int k = 0; k < H_DIM + NF_DIM; ++k) acc += r[k] * Wf1[k * H_DIM + c];
  q1[(size_t)gid * H_DIM + c] = fmaxf(acc, 0.f);
}

// ---------------- q2 = relu(q1 @ Wf2 + bf2) --------------------------------
__global__ __launch_bounds__(128) void k_f2(
    const float* __restrict__ q1, const float* __restrict__ Wf2,
    const float* __restrict__ bf2, float* __restrict__ q2) {
  int gid = blockIdx.x;
  int c = threadIdx.x;
  __shared__ float r[H_DIM];
  for (int i = c; i < H_DIM; i += 128) r[i] = q1[(size_t)gid * H_DIM + i];
  __syncthreads();
  float acc = bf2[c];
#pragma unroll 8
  for (int k = 0; k < H_DIM; ++k) acc += r[k] * Wf2[k * 128 + c];
  q2[(size_t)gid * 128 + c] = fmaxf(acc, 0.f);
}

// ---------------- edl head -------------------------------------------------
__device__ __forceinline__ float softplusf(float x) {
  return fmaxf(x, 0.f) + log1pf(expf(-fabsf(x)));
}

__global__ __launch_bounds__(64) void k_head(
    const float* __restrict__ q2, const float* __restrict__ Wh,
    const float* __restrict__ bh, float* __restrict__ out) {
  int gid = blockIdx.x;
  int t = threadIdx.x;
  __shared__ float r[128];
  for (int i = t; i < 128; i += 64) r[i] = q2[(size_t)gid * 128 + i];
  __syncthreads();
  if (t < 4) {
    float acc = bh[t];
#pragma unroll 8
    for (int k = 0; k < 128; ++k) acc += r[k] * Wh[k * 4 + t];
    float v;
    if (t == 0) v = acc;
    else if (t == 2) v = softplusf(acc) + 1.f + 1e-6f;
    else v = softplusf(acc) + 1e-6f;
    out[(size_t)gid * 4 + t] = v;
  }
}

extern "C" void kernel_launch(void* const* d_in, const int* in_sizes, int n_in,
                              void* d_out, int out_size, void* d_ws, size_t ws_size,
                              hipStream_t stream) {
  const float* x     = (const float*)d_in[0];
  const int*   ei    = (const int*)d_in[1];
  const float* ea    = (const float*)d_in[2];
  const int*   batch = (const int*)d_in[3];
  const float* gf    = (const float*)d_in[4];
  const float* Win   = (const float*)d_in[5];
  const float* bin   = (const float*)d_in[6];
  const float* We    = (const float*)d_in[7];
  const float* be    = (const float*)d_in[8];
  const float* Wl1   = (const float*)d_in[9];
  const float* bl1   = (const float*)d_in[10];
  const float* Wl2   = (const float*)d_in[11];
  const float* bl2   = (const float*)d_in[12];
  const float* bnw   = (const float*)d_in[13];
  const float* bnb   = (const float*)d_in[14];
  const float* bnm   = (const float*)d_in[15];
  const float* bnv   = (const float*)d_in[16];
  const float* Wp1   = (const float*)d_in[17];
  const float* bp1   = (const float*)d_in[18];
  const float* Wp2   = (const float*)d_in[19];
  const float* bp2   = (const float*)d_in[20];
  const float* Wf1   = (const float*)d_in[21];
  const float* bf1   = (const float*)d_in[22];
  const float* Wf2   = (const float*)d_in[23];
  const float* bf2   = (const float*)d_in[24];
  const float* Wh    = (const float*)d_in[25];
  const float* bh    = (const float*)d_in[26];
  float* out = (float*)d_out;

  const int* srcs = ei;
  const int* dsts = ei + N_EDGES;

  const size_t NH = (size_t)N_NODES * H_DIM;
  float* h  = (float*)d_ws;
  float* g  = h + NH;
  float* z1 = g + (size_t)G_GRAPHS * H_DIM;
  float* q1 = z1 + (size_t)G_GRAPHS * 128;
  float* q2 = q1 + (size_t)G_GRAPHS * H_DIM;
  bf16_t* t0b = (bf16_t*)(q2 + (size_t)G_GRAPHS * 128);
  bf16_t* t1b = t0b + NH;
  bf16_t* Wt1 = t1b + NH;                    // 4*65536
  bf16_t* Wt2 = Wt1 + (size_t)L_LAYERS * 65536;
  int* deg  = (int*)(Wt2 + (size_t)L_LAYERS * 65536);
  int* fill = deg + N_NODES;
  int* incl = fill + N_NODES;
  int* off  = incl + N_NODES;       // N_NODES + 1
  int* bsum = off + N_NODES + 1;    // 128
  int* eid  = bsum + 128;           // N_EDGES
  int* src_csr = eid + N_EDGES;     // N_EDGES

  // ---- one-time prep: CSR build + weight transpose/cast + input proj ----
  hipMemsetAsync(deg, 0, N_NODES * sizeof(int), stream);
  hipMemsetAsync(fill, 0, N_NODES * sizeof(int), stream);
  const int nscan = (N_NODES + SCAN_B - 1) / SCAN_B;
  k_deg<<<(N_EDGES + 255) / 256, 256, 0, stream>>>(dsts, deg);
  k_scan1<<<nscan, SCAN_B, 0, stream>>>(deg, incl, bsum);
  k_scan2<<<1, 64, 0, stream>>>(bsum, nscan);
  k_scan3<<<nscan, SCAN_B, 0, stream>>>(incl, deg, bsum, off);
  k_scatter<<<(N_EDGES + 255) / 256, 256, 0, stream>>>(srcs, dsts, off, fill, eid, src_csr);
  dim3 wgrid(256, L_LAYERS);
  k_prepW<<<wgrid, 256, 0, stream>>>(Wl1, Wt1);
  k_prepW<<<wgrid, 256, 0, stream>>>(Wl2, Wt2);
  k_init_h<<<N_NODES, 256, 0, stream>>>(x, Win, bin, h);

  dim3 mmg((N_NODES + GBM - 1) / GBM, H_DIM / GBN);
  for (int l = 0; l < L_LAYERS; ++l) {
    k_aggr<<<N_NODES, 256, 0, stream>>>(off, src_csr, eid, ea, h,
                                        We + (size_t)l * EF_DIM * H_DIM,
                                        be + l * H_DIM, t0b);
    k_mm<0><<<mmg, 256, 0, stream>>>(t0b, Wt1 + (size_t)l * 65536,
                                     bl1 + l * H_DIM, nullptr, nullptr, nullptr,
                                     nullptr, t1b, nullptr);
    k_mm<1><<<mmg, 256, 0, stream>>>(t1b, Wt2 + (size_t)l * 65536,
                                     bl2 + l * H_DIM, bnw + l * H_DIM,
                                     bnb + l * H_DIM, bnm + l * H_DIM,
                                     bnv + l * H_DIM, nullptr, h);
  }

  float* out_g = out + 2048 + (size_t)G_GRAPHS * 64;  // edl(2048) + z(32768)
  k_pool<<<G_GRAPHS, 256, 0, stream>>>(batch, h, g, out_g);
  k_p1<<<G_GRAPHS, 128, 0, stream>>>(g, Wp1, bp1, z1);
  k_p2<<<G_GRAPHS, 64, 0, stream>>>(z1, Wp2, bp2, out);
  k_f1<<<G_GRAPHS, 256, 0, stream>>>(g, gf, Wf1, bf1, q1);
  k_f2<<<G_GRAPHS, 128, 0, stream>>>(q1, Wf2, bf2, q2);
  k_head<<<G_GRAPHS, 64, 0, stream>>>(q2, Wh, bh, out);
}